// Round 8
// baseline (318.144 us; speedup 1.0000x reference)
//
#include <hip/hip_runtime.h>
#include <math.h>

#define B_  4
#define L_  8192
#define D_  512
#define BL_ (B_*L_)
#define TOK 32
#define XS  36            // xt/pf row stride: 16B-aligned, ==4 mod 32
#define KC  16
#define NCH (D_/KC)

// ---------------------------------------------------------------------------
// Signal + e, LDS-staged weights with software-pipelined (register) prefetch:
// issue chunk c+1 global loads after conv(c); LDS write at end of chunk ->
// vmcnt drain is ~1100cy after issue, fully hidden behind GEMM compute.
// ---------------------------------------------------------------------------
__global__ __launch_bounds__(256, 4) void k_signal(
    const float* __restrict__ x, const float* __restrict__ mask,
    const float* __restrict__ W1, const float* __restrict__ b1,
    const float* __restrict__ W2, const float* __restrict__ b2,
    const float* __restrict__ Wc, const float* __restrict__ bc,
    const float* __restrict__ Wb1, const float* __restrict__ bb1,
    const float* __restrict__ Wb2, const float* __restrict__ bb2,
    float* __restrict__ signal, float* __restrict__ e)
{
  __shared__ float ws1[KC][128];   // W1 chunk rows kc..kc+15
  __shared__ float wsb[KC][128];   // Wb1 x-part chunk
  __shared__ float wsp[8][128];    // Wb1 pf-part chunk (8 conv channels/chunk)
  __shared__ float xt[KC][XS];     // x transposed; col 32 = l0-1, 33 = l0+32
  __shared__ float pf[8][XS];      // conv out chunk

  const int t   = threadIdx.x;
  const int blk = blockIdx.x;          // 1024 = 4 b x 256 tiles
  const int b   = blk >> 8;
  const int l0  = (blk & 255) * TOK;
  const float* xb = x + (size_t)b * L_ * D_;

  const int jq = t & 31, tw = t >> 5;
  const int j0 = jq << 2, tok0 = tw << 2;

  const int stok = t >> 2, skk = t & 3;     // x-staging role (t<128)
  const int oo_c  = t >> 5;                 // conv role: out-ch 0..7
  const int tokc  = t & 31;
  const int cb_c  = (oo_c >> 1) << 2;

  const int row = t >> 5, c4 = (t & 31) << 2;   // weight staging role

  float a1[4][4], a2[4][4];
#pragma unroll
  for (int i = 0; i < 4; ++i)
#pragma unroll
    for (int j = 0; j < 4; ++j) { a1[i][j] = 0.f; a2[i][j] = 0.f; }
  float esacc = 0.f;

  float4 r_w1a, r_w1b, r_wba, r_wbb, r_wp, r_x;
  float4 r_wc0, r_wc1, r_wc2;
  float  r_bc;

#define ISSUE_LOADS(cc) do {                                                    \
    const int kc_ = (cc) << 4;                                                  \
    r_w1a = *reinterpret_cast<const float4*>(W1 + (size_t)(kc_ + row) * 128 + c4);       \
    r_w1b = *reinterpret_cast<const float4*>(W1 + (size_t)(kc_ + 8 + row) * 128 + c4);   \
    r_wba = *reinterpret_cast<const float4*>(Wb1 + (size_t)(kc_ + row) * 128 + c4);      \
    r_wbb = *reinterpret_cast<const float4*>(Wb1 + (size_t)(kc_ + 8 + row) * 128 + c4);  \
    r_wp  = *reinterpret_cast<const float4*>(Wb1 + (size_t)(512 + ((cc) << 3) + row) * 128 + c4); \
    {                                                                           \
      const int o_ = ((cc) << 3) + oo_c;                                        \
      const float* wcp_ = Wc + o_ * 12;                                         \
      r_wc0 = *reinterpret_cast<const float4*>(wcp_);                           \
      r_wc1 = *reinterpret_cast<const float4*>(wcp_ + 4);                       \
      r_wc2 = *reinterpret_cast<const float4*>(wcp_ + 8);                       \
      r_bc  = bc[o_];                                                           \
    }                                                                           \
    if (t < 128) {                                                              \
      r_x = *reinterpret_cast<const float4*>(xb + (size_t)(l0 + stok) * D_ + kc_ + (skk << 2)); \
    } else if (t < 136) {                                                       \
      const int q_ = t - 128;                                                   \
      const int l_ = (q_ >> 2) ? (l0 + TOK) : (l0 - 1);                         \
      r_x = make_float4(0.f, 0.f, 0.f, 0.f);                                    \
      if (l_ >= 0 && l_ < L_)                                                   \
        r_x = *reinterpret_cast<const float4*>(xb + (size_t)l_ * D_ + kc_ + ((q_ & 3) << 2)); \
    }                                                                           \
  } while (0)

#define WRITE_LDS() do {                                                        \
    *reinterpret_cast<float4*>(&ws1[row][c4]) = r_w1a;                          \
    *reinterpret_cast<float4*>(&ws1[8 + row][c4]) = r_w1b;                      \
    *reinterpret_cast<float4*>(&wsb[row][c4]) = r_wba;                          \
    *reinterpret_cast<float4*>(&wsb[8 + row][c4]) = r_wbb;                      \
    *reinterpret_cast<float4*>(&wsp[row][c4]) = r_wp;                           \
    if (t < 128) {                                                              \
      esacc = fmaf(r_x.x, r_x.x, esacc); esacc = fmaf(r_x.y, r_x.y, esacc);     \
      esacc = fmaf(r_x.z, r_x.z, esacc); esacc = fmaf(r_x.w, r_x.w, esacc);     \
      const int r_ = skk << 2;                                                  \
      xt[r_ + 0][stok] = r_x.x; xt[r_ + 1][stok] = r_x.y;                       \
      xt[r_ + 2][stok] = r_x.z; xt[r_ + 3][stok] = r_x.w;                       \
    } else if (t < 136) {                                                       \
      const int q_ = t - 128; const int kk_ = q_ & 3;                           \
      const int col_ = TOK + (q_ >> 2); const int r_ = kk_ << 2;                \
      xt[r_ + 0][col_] = r_x.x; xt[r_ + 1][col_] = r_x.y;                       \
      xt[r_ + 2][col_] = r_x.z; xt[r_ + 3][col_] = r_x.w;                       \
    }                                                                           \
  } while (0)

  ISSUE_LOADS(0);
  WRITE_LDS();

  for (int c = 0; c < NCH; ++c) {
    __syncthreads();                   // chunk c LDS visible

    // ---- conv(c): uses conv regs loaded by ISSUE(c) ----
    {
      const float wc12[12] = {r_wc0.x, r_wc0.y, r_wc0.z, r_wc0.w,
                              r_wc1.x, r_wc1.y, r_wc1.z, r_wc1.w,
                              r_wc2.x, r_wc2.y, r_wc2.z, r_wc2.w};
      float acc = r_bc;
      const int tm1 = (tokc == 0) ? TOK : tokc - 1;
      const int tp1 = (tokc == TOK - 1) ? TOK + 1 : tokc + 1;
#pragma unroll
      for (int i = 0; i < 4; ++i) {
        const float* rowp = &xt[cb_c + i][0];
        acc = fmaf(rowp[tm1],  wc12[i * 3 + 0], acc);
        acc = fmaf(rowp[tokc], wc12[i * 3 + 1], acc);
        acc = fmaf(rowp[tp1],  wc12[i * 3 + 2], acc);
      }
      pf[oo_c][tokc] = acc;
    }

    // ---- issue chunk c+1 global loads (latency hidden behind GEMMs) ----
    if (c + 1 < NCH) ISSUE_LOADS(c + 1);

    // ---- GEMM x-part from LDS weights ----
#pragma unroll 4
    for (int k = 0; k < KC; ++k) {
      const float4 w1 = *reinterpret_cast<const float4*>(&ws1[k][j0]);
      const float4 wb = *reinterpret_cast<const float4*>(&wsb[k][j0]);
      const float4 xv = *reinterpret_cast<const float4*>(&xt[k][tok0]);
      const float xs4[4] = {xv.x, xv.y, xv.z, xv.w};
#pragma unroll
      for (int i = 0; i < 4; ++i) {
        a1[i][0] = fmaf(xs4[i], w1.x, a1[i][0]);
        a1[i][1] = fmaf(xs4[i], w1.y, a1[i][1]);
        a1[i][2] = fmaf(xs4[i], w1.z, a1[i][2]);
        a1[i][3] = fmaf(xs4[i], w1.w, a1[i][3]);
        a2[i][0] = fmaf(xs4[i], wb.x, a2[i][0]);
        a2[i][1] = fmaf(xs4[i], wb.y, a2[i][1]);
        a2[i][2] = fmaf(xs4[i], wb.z, a2[i][2]);
        a2[i][3] = fmaf(xs4[i], wb.w, a2[i][3]);
      }
    }
    __syncthreads();                   // pf writes visible

    // ---- GEMM pf-part from LDS weights ----
#pragma unroll 4
    for (int oo = 0; oo < 8; ++oo) {
      const float4 wp = *reinterpret_cast<const float4*>(&wsp[oo][j0]);
      const float4 pv = *reinterpret_cast<const float4*>(&pf[oo][tok0]);
      const float ps4[4] = {pv.x, pv.y, pv.z, pv.w};
#pragma unroll
      for (int i = 0; i < 4; ++i) {
        a2[i][0] = fmaf(ps4[i], wp.x, a2[i][0]);
        a2[i][1] = fmaf(ps4[i], wp.y, a2[i][1]);
        a2[i][2] = fmaf(ps4[i], wp.z, a2[i][2]);
        a2[i][3] = fmaf(ps4[i], wp.w, a2[i][3]);
      }
    }

    if (c + 1 < NCH) {
      __syncthreads();                 // all LDS reads of chunk c done
      WRITE_LDS();                     // vmcnt drain here — loads long landed
    }
  }

  // ---- epilogue: relu, project, cross-jq reduce, sigmoid ----
  {
    float b1v[4], w2v[4], bbv[4], wv2[4];
#pragma unroll
    for (int jj = 0; jj < 4; ++jj) {
      b1v[jj] = b1[j0 + jj];  w2v[jj] = W2[j0 + jj];
      bbv[jj] = bb1[j0 + jj]; wv2[jj] = Wb2[j0 + jj];
    }
    const float bias2 = b2[0], biasb2 = bb2[0];
#pragma unroll
    for (int i = 0; i < 4; ++i) {
      float p1 = 0.f, p2 = 0.f;
#pragma unroll
      for (int jj = 0; jj < 4; ++jj) {
        const float h1 = a1[i][jj] + b1v[jj];
        if (h1 > 0.f) p1 = fmaf(h1, w2v[jj], p1);
        const float h2 = a2[i][jj] + bbv[jj];
        if (h2 > 0.f) p2 = fmaf(h2, wv2[jj], p2);
      }
#pragma unroll
      for (int off = 1; off < 32; off <<= 1) {
        p1 += __shfl_xor(p1, off, 64);
        p2 += __shfl_xor(p2, off, 64);
      }
      if (jq == 0) {
        const int gi = b * L_ + l0 + tok0 + i;
        const float content = 1.f / (1.f + expf(-(p1 + bias2)));
        const float bscore  = 1.f / (1.f + expf(-(p2 + biasb2)));
        signal[gi] = content * (1.f - bscore) * mask[gi];
      }
    }
  }

  // ---- e epilogue: reduce over the 4 skk lanes of each token ----
  if (t < 128) {
    float es = esacc;
    es += __shfl_xor(es, 1, 64);
    es += __shfl_xor(es, 2, 64);
    if (skk == 0) {
      const int gi = b * L_ + l0 + stok;
      const float m = mask[gi];
      e[gi] = m * m * es;
    }
  }
#undef ISSUE_LOADS
#undef WRITE_LDS
}

// ---------------------------------------------------------------------------
// Fused quantile + enforce. One block (1024 thr) per batch row.
// Rounds 0-1 use match-any ballot counting (signal values cluster into a few
// exponent bins -> LDS atomics serialize ~64-way); rounds 2-3 use atomics.
// ---------------------------------------------------------------------------
__device__ __forceinline__ int chain_sim(unsigned long long w, int from) {
  int last = -1;
  while (from < 64) {
    const unsigned long long m = w & (~0ull << from);
    if (m == 0ull) break;
    const int p = __ffsll(m) - 1;
    last = p;
    from = p + 4;
  }
  return last;
}

__global__ __launch_bounds__(1024) void k_select(
    const float* __restrict__ signal,
    int* __restrict__ starts, int* __restrict__ nlast, float* __restrict__ bounds)
{
  __shared__ unsigned int bins[4][256];
  __shared__ unsigned int sel_prefix;
  __shared__ int sel_rank;
  __shared__ float sh_thr;
  __shared__ unsigned int wmin[16];
  __shared__ int wcnt[16];
  __shared__ unsigned long long cw[128];
  __shared__ unsigned char nb[L_];
  __shared__ signed char tbl[128][4];
  __shared__ int st_in[128];
  __shared__ int tsum[256];
  __shared__ int offs[257];

  const int b = blockIdx.x, t = threadIdx.x;
  const int wv = t >> 6, lane = t & 63;
  const float* s = signal + b * L_;

  float val[8];
  unsigned int key[8];
#pragma unroll
  for (int i = 0; i < 8; ++i) {
    val[i] = s[(i << 10) + t];
    const unsigned int u = __float_as_uint(val[i]);
    key[i] = (u & 0x80000000u) ? ~u : (u | 0x80000000u);
  }

  // ---- radix select rank 5733 = floor(0.7*(L-1)) ----
  if (t == 0) { sel_prefix = 0u; sel_rank = 5733; }
  __syncthreads();
  for (int round = 0; round < 4; ++round) {
    reinterpret_cast<unsigned int*>(bins)[t] = 0u;
    __syncthreads();
    const unsigned int pre = sel_prefix;
    const int shift = 24 - 8 * round;
    if (round < 2) {
#pragma unroll
      for (int i = 0; i < 8; ++i) {
        const bool act = (round == 0) || ((key[i] >> (shift + 8)) == pre);
        const unsigned int bin = (key[i] >> shift) & 255u;
        unsigned long long peers = __ballot(act);
#pragma unroll
        for (int bit = 0; bit < 8; ++bit) {
          const bool myb = (bin >> bit) & 1;
          const unsigned long long bb = __ballot(act && myb);
          peers &= myb ? bb : ~bb;
        }
        if (act) {
          const int leader = __ffsll(peers) - 1;
          if (lane == leader)
            atomicAdd(&bins[wv >> 2][bin], (unsigned int)__popcll(peers));
        }
      }
    } else {
#pragma unroll
      for (int i = 0; i < 8; ++i) {
        if ((key[i] >> (shift + 8)) == pre)
          atomicAdd(&bins[wv >> 2][(key[i] >> shift) & 255u], 1u);
      }
    }
    __syncthreads();
    if (t < 256)
      bins[0][t] = bins[0][t] + bins[1][t] + bins[2][t] + bins[3][t];
    __syncthreads();
    if (t < 64) {
      const unsigned int c0 = bins[0][(t << 2) + 0], c1 = bins[0][(t << 2) + 1];
      const unsigned int c2 = bins[0][(t << 2) + 2], c3 = bins[0][(t << 2) + 3];
      const unsigned int lsum = c0 + c1 + c2 + c3;
      unsigned int run = lsum;
#pragma unroll
      for (int off = 1; off < 64; off <<= 1) {
        const unsigned int v = __shfl_up(run, off, 64);
        if (t >= off) run += v;
      }
      const int r = sel_rank;
      if (r >= (int)(run - lsum) && r < (int)run) {
        int rr = r - (int)(run - lsum);
        unsigned int cbin;
        if (rr < (int)c0) { cbin = 0; }
        else if (rr < (int)(c0 + c1)) { cbin = 1; rr -= (int)c0; }
        else if (rr < (int)(c0 + c1 + c2)) { cbin = 2; rr -= (int)(c0 + c1); }
        else { cbin = 3; rr -= (int)(c0 + c1 + c2); }
        sel_rank = rr;
        sel_prefix = (pre << 8) | ((unsigned int)(t << 2) | cbin);
      }
    }
    __syncthreads();
  }
  const unsigned int k0 = sel_prefix;

  // ---- successor: count <=k0 and min of keys > k0 (tie-safe) ----
  {
    int cle = 0;
    unsigned int mgt = 0xFFFFFFFFu;
#pragma unroll
    for (int i = 0; i < 8; ++i) {
      if (key[i] <= k0) ++cle;
      else mgt = min(mgt, key[i]);
    }
#pragma unroll
    for (int off = 1; off < 64; off <<= 1) {
      cle += __shfl_xor(cle, off, 64);
      mgt = min(mgt, (unsigned int)__shfl_xor((int)mgt, off, 64));
    }
    if (lane == 0) { wcnt[wv] = cle; wmin[wv] = mgt; }
    __syncthreads();
    if (t == 0) {
      int C = 0; unsigned int M = 0xFFFFFFFFu;
      for (int g = 0; g < 16; ++g) { C += wcnt[g]; M = min(M, wmin[g]); }
      const unsigned int k1 = (C >= 5735) ? k0 : M;
      const unsigned int u0 = (k0 & 0x80000000u) ? (k0 & 0x7fffffffu) : ~k0;
      const unsigned int u1 = (k1 & 0x80000000u) ? (k1 & 0x7fffffffu) : ~k1;
      const float v0 = __uint_as_float(u0);
      const float v1 = __uint_as_float(u1);
      const float g = 0.7f * 8191.0f - 5733.0f;
      sh_thr = v0 + g * (v1 - v0);
    }
    __syncthreads();
  }
  const float thr = sh_thr;

  // ---- candidate bitmap from register values ----
#pragma unroll
  for (int i = 0; i < 8; ++i) {
    const unsigned long long m = __ballot(val[i] < thr);
    if (lane == 0) cw[(i << 4) + wv] = m;
  }
  {
    const int base = t << 3;
#pragma unroll
    for (int i = 0; i < 8; ++i) nb[base + i] = 0;
  }
  __syncthreads();
  if (t == 0) cw[127] |= (1ull << 63);   // forced candidate at L-1
  __syncthreads();

  // ---- (1) per-64-block transition tables ----
  if (t < 512) {
    const int blk = t >> 2, cls = t & 3;
    tbl[blk][cls] = (signed char)chain_sim(cw[blk], cls);
  }
  __syncthreads();

  // ---- (2) serial 128-step state scan ----
  if (t == 0) {
    int st = 0;
    for (int blk = 0; blk < 128; ++blk) {
      const int bs = blk << 6;
      st_in[blk] = st;
      int pl;
      if (blk == 0) {
        pl = chain_sim(cw[0], 4);
      } else {
        int off = st + 4 - bs;
        if (off < 0) off = 0;
        pl = tbl[blk][off];
      }
      if (pl >= 0) st = bs + pl;
    }
  }
  __syncthreads();

  // ---- (3) parallel emission of acceptance + split bytes ----
  if (t < 128) {
    const int bs = t << 6;
    const unsigned long long w = cw[t];
    int st = st_in[t];
    int from = st + 4 - bs;
    if (from < 0) from = 0;
    while (from < 64) {
      const unsigned long long m = w & (~0ull << from);
      if (m == 0ull) break;
      const int p_rel = __ffsll(m) - 1;
      const int p = bs + p_rel;
      nb[p] = 1;
      const int ps = p - st;
      const int k = (ps + 15) >> 4;
      if (k > 1) {
        int sz = ps / k; if (sz < 1) sz = 1;
        for (int j = 1; j < k; ++j) nb[st + j * sz] = 1;
      }
      st = p;
      from = p_rel + 4;
    }
  }
  __syncthreads();

  // ---- prefix scan -> starts / nlast / bounds ----
  if (t < 256) {
    const int base = t << 5;
    int ls = 0;
    for (int i = 0; i < 32; ++i) ls += nb[base + i];
    tsum[t] = ls;
  }
  __syncthreads();
  if (t == 0) {
    int r = 0;
    for (int i = 0; i < 256; ++i) { offs[i] = r; r += tsum[i]; }
    offs[256] = r;
  }
  __syncthreads();
  if (t < 256) {
    const int base = t << 5;
    int run = offs[t];
    for (int i = 0; i < 32; ++i) {
      run += nb[base + i];
      if (nb[base + i]) starts[b * L_ + run] = base + i;
    }
  }
  if (t == 0) { starts[b * L_ + 0] = 0; nlast[b] = offs[256]; }
  __syncthreads();
  const int total = offs[256];
  for (int i = t; i < L_; i += 1024)
    bounds[b * L_ + i] = (i >= 1 && i <= total) ? 1.0f : 0.0f;
}

// ---------------------------------------------------------------------------
// Segment softmax-merge: one wave per segment id; dead sids write zeros.
// ---------------------------------------------------------------------------
__global__ __launch_bounds__(64) void k_merge(const float* __restrict__ x,
    const float* __restrict__ mask, const float* __restrict__ e,
    const int* __restrict__ starts, const int* __restrict__ nlast,
    float* __restrict__ merged)
{
  const int idx = blockIdx.x;
  const int b   = idx >> 13;
  const int sid = idx & (L_ - 1);
  const int n = nlast[b];
  const int lane = threadIdx.x;
  const int c0 = lane << 3;
  float* o = merged + (size_t)(b * L_ + sid) * D_ + c0;
  if (sid > n) {
    const float4 z = make_float4(0.f, 0.f, 0.f, 0.f);
    reinterpret_cast<float4*>(o)[0] = z;
    reinterpret_cast<float4*>(o)[1] = z;
    return;
  }
  const int t0 = starts[b * L_ + sid];
  const int t1 = (sid < n) ? starts[b * L_ + sid + 1] : L_;
  const float* eb = e + b * L_;

  float mx = -INFINITY;
  for (int p = t0; p < t1; ++p) mx = fmaxf(mx, eb[p]);
  float den = 0.f;
  for (int p = t0; p < t1; ++p) den += expf(eb[p] - mx);

  float acc[8] = {0,0,0,0,0,0,0,0};
  for (int p = t0; p < t1; ++p) {
    const float wn = expf(eb[p] - mx) / den;
    const float sc = wn * mask[b * L_ + p];
    const float* xr = x + ((size_t)(b * L_ + p)) * D_ + c0;
    const float4 u0 = reinterpret_cast<const float4*>(xr)[0];
    const float4 u1 = reinterpret_cast<const float4*>(xr)[1];
    acc[0] = fmaf(sc, u0.x, acc[0]); acc[1] = fmaf(sc, u0.y, acc[1]);
    acc[2] = fmaf(sc, u0.z, acc[2]); acc[3] = fmaf(sc, u0.w, acc[3]);
    acc[4] = fmaf(sc, u1.x, acc[4]); acc[5] = fmaf(sc, u1.y, acc[5]);
    acc[6] = fmaf(sc, u1.z, acc[6]); acc[7] = fmaf(sc, u1.w, acc[7]);
  }
  reinterpret_cast<float4*>(o)[0] = make_float4(acc[0], acc[1], acc[2], acc[3]);
  reinterpret_cast<float4*>(o)[1] = make_float4(acc[4], acc[5], acc[6], acc[7]);
}

// ---------------------------------------------------------------------------
extern "C" void kernel_launch(void* const* d_in, const int* in_sizes, int n_in,
                              void* d_out, int out_size, void* d_ws, size_t ws_size,
                              hipStream_t stream) {
  (void)in_sizes; (void)n_in; (void)out_size; (void)ws_size;
  const float* x    = (const float*)d_in[0];
  const float* mask = (const float*)d_in[1];
  const float* W1   = (const float*)d_in[2];
  const float* b1   = (const float*)d_in[3];
  const float* W2   = (const float*)d_in[4];
  const float* b2   = (const float*)d_in[5];
  const float* Wc   = (const float*)d_in[6];
  const float* bc   = (const float*)d_in[7];
  const float* Wb1  = (const float*)d_in[8];
  const float* bb1  = (const float*)d_in[9];
  const float* Wb2  = (const float*)d_in[10];
  const float* bb2  = (const float*)d_in[11];

  float* merged = (float*)d_out;
  float* bounds = (float*)d_out + (size_t)BL_ * D_;

  char* ws = (char*)d_ws;
  float* signal = (float*)(ws);
  float* e      = (float*)(ws + (size_t)BL_ * 4);
  int*   starts = (int*)  (ws + (size_t)BL_ * 8);
  int*   nlast  = (int*)  (ws + (size_t)BL_ * 12);

  k_signal<<<BL_ / TOK, 256, 0, stream>>>(x, mask, W1, b1, W2, b2, Wc, bc,
                                          Wb1, bb1, Wb2, bb2, signal, e);
  k_select<<<B_, 1024, 0, stream>>>(signal, starts, nlast, bounds);
  k_merge<<<BL_, 64, 0, stream>>>(x, mask, e, starts, nlast, merged);
}

// Round 9
// 316.480 us; speedup vs baseline: 1.0053x; 1.0053x over previous
//
#include <hip/hip_runtime.h>
#include <math.h>

#define B_  4
#define L_  8192
#define D_  512
#define BL_ (B_*L_)
#define TOK 32
#define XS  36            // xt/pf row stride: 16B-aligned, ==4 mod 32
#define KC  16
#define NCH (D_/KC)

// async 16B/lane global->LDS: LDS dest = wave-uniform base + lane*16
#define ASYNC16(gp, lp)                                                   \
  __builtin_amdgcn_global_load_lds(                                       \
      (const __attribute__((address_space(1))) void*)(gp),                \
      (__attribute__((address_space(3))) void*)(lp), 16, 0, 0)

// ---------------------------------------------------------------------------
// Signal + e. Weights staged via hardware-async global_load_lds issued after
// the mid barrier (cover = pf-GEMM), drained by the loop-top barrier.
// wsp double-buffered; 2 barriers/chunk. 5 blocks/CU (28KB LDS).
// ---------------------------------------------------------------------------
__global__ __launch_bounds__(256, 5) void k_signal(
    const float* __restrict__ x, const float* __restrict__ mask,
    const float* __restrict__ W1, const float* __restrict__ b1,
    const float* __restrict__ W2, const float* __restrict__ b2,
    const float* __restrict__ Wc, const float* __restrict__ bc,
    const float* __restrict__ Wb1, const float* __restrict__ bb1,
    const float* __restrict__ Wb2, const float* __restrict__ bb2,
    float* __restrict__ signal, float* __restrict__ e)
{
  __shared__ float ws1[KC][128];      // 8KB  W1 chunk
  __shared__ float wsb[KC][128];      // 8KB  Wb1 x-part chunk
  __shared__ float wsp[2][8][128];    // 8KB  Wb1 pf-part, double-buffered
  __shared__ float xt[KC][XS];        // 2.25KB x transposed (+2 halo cols)
  __shared__ float pf[8][XS];         // 1.1KB conv out chunk

  const int t   = threadIdx.x;
  const int blk = blockIdx.x;          // 1024 = 4 b x 256 tiles
  const int b   = blk >> 8;
  const int l0  = (blk & 255) * TOK;
  const float* xb = x + (size_t)b * L_ * D_;

  const int jq = t & 31, tw = t >> 5;
  const int j0 = jq << 2, tok0 = tw << 2;

  const int stok = t >> 2, skk = t & 3;     // x-staging role (t<128)
  const int oo_c  = t >> 5;                 // conv role: out-ch 0..7
  const int tokc  = t & 31;
  const int cb_c  = (oo_c >> 1) << 2;

  float a1[4][4], a2[4][4];
#pragma unroll
  for (int i = 0; i < 4; ++i)
#pragma unroll
    for (int j = 0; j < 4; ++j) { a1[i][j] = 0.f; a2[i][j] = 0.f; }
  float esacc = 0.f;

  float4 r_x, r_wc0, r_wc1, r_wc2;
  float  r_bc;

#define ISSUE_WEIGHTS(cc) do {                                                  \
    const int kc_ = (cc) << 4;                                                  \
    const float* g1 = W1  + (size_t)kc_ * 128 + (t << 2);                       \
    const float* gb = Wb1 + (size_t)kc_ * 128 + (t << 2);                       \
    const float* gp = Wb1 + (size_t)(512 + ((cc) << 3)) * 128 + (t << 2);       \
    float* l1 = &ws1[0][0] + ((t >> 6) << 8);                                   \
    float* lb = &wsb[0][0] + ((t >> 6) << 8);                                   \
    float* lp = &wsp[(cc) & 1][0][0] + ((t >> 6) << 8);                         \
    ASYNC16(g1, l1);  ASYNC16(g1 + 1024, l1 + 1024);                            \
    ASYNC16(gb, lb);  ASYNC16(gb + 1024, lb + 1024);                            \
    ASYNC16(gp, lp);                                                            \
  } while (0)

#define LOAD_REGS(cc) do {                                                      \
    const int kc_ = (cc) << 4;                                                  \
    const int o_ = ((cc) << 3) + oo_c;                                          \
    const float* wcp_ = Wc + o_ * 12;                                           \
    r_wc0 = *reinterpret_cast<const float4*>(wcp_);                             \
    r_wc1 = *reinterpret_cast<const float4*>(wcp_ + 4);                         \
    r_wc2 = *reinterpret_cast<const float4*>(wcp_ + 8);                         \
    r_bc  = bc[o_];                                                             \
    if (t < 128) {                                                              \
      r_x = *reinterpret_cast<const float4*>(                                   \
          xb + (size_t)(l0 + stok) * D_ + kc_ + (skk << 2));                    \
    } else if (t < 136) {                                                       \
      const int q_ = t - 128;                                                   \
      const int l_ = (q_ >> 2) ? (l0 + TOK) : (l0 - 1);                         \
      r_x = make_float4(0.f, 0.f, 0.f, 0.f);                                    \
      if (l_ >= 0 && l_ < L_)                                                   \
        r_x = *reinterpret_cast<const float4*>(                                 \
            xb + (size_t)l_ * D_ + kc_ + ((q_ & 3) << 2));                      \
    }                                                                           \
  } while (0)

#define WRITE_XT() do {                                                         \
    if (t < 128) {                                                              \
      esacc = fmaf(r_x.x, r_x.x, esacc); esacc = fmaf(r_x.y, r_x.y, esacc);     \
      esacc = fmaf(r_x.z, r_x.z, esacc); esacc = fmaf(r_x.w, r_x.w, esacc);     \
      const int r_ = skk << 2;                                                  \
      xt[r_ + 0][stok] = r_x.x; xt[r_ + 1][stok] = r_x.y;                       \
      xt[r_ + 2][stok] = r_x.z; xt[r_ + 3][stok] = r_x.w;                       \
    } else if (t < 136) {                                                       \
      const int q_ = t - 128; const int kk_ = q_ & 3;                           \
      const int col_ = TOK + (q_ >> 2); const int r_ = kk_ << 2;                \
      xt[r_ + 0][col_] = r_x.x; xt[r_ + 1][col_] = r_x.y;                       \
      xt[r_ + 2][col_] = r_x.z; xt[r_ + 3][col_] = r_x.w;                       \
    }                                                                           \
  } while (0)

  // prologue: chunk 0
  ISSUE_WEIGHTS(0);
  LOAD_REGS(0);
  WRITE_XT();

  for (int c = 0; c < NCH; ++c) {
    __syncthreads();   // (A) drains async weight loads + xt writes of prev iter

    // ---- conv(c): regs loaded last iter; reads xt; writes pf ----
    {
      const float wc12[12] = {r_wc0.x, r_wc0.y, r_wc0.z, r_wc0.w,
                              r_wc1.x, r_wc1.y, r_wc1.z, r_wc1.w,
                              r_wc2.x, r_wc2.y, r_wc2.z, r_wc2.w};
      float acc = r_bc;
      const int tm1 = (tokc == 0) ? TOK : tokc - 1;
      const int tp1 = (tokc == TOK - 1) ? TOK + 1 : tokc + 1;
#pragma unroll
      for (int i = 0; i < 4; ++i) {
        const float* rowp = &xt[cb_c + i][0];
        acc = fmaf(rowp[tm1],  wc12[i * 3 + 0], acc);
        acc = fmaf(rowp[tokc], wc12[i * 3 + 1], acc);
        acc = fmaf(rowp[tp1],  wc12[i * 3 + 2], acc);
      }
      pf[oo_c][tokc] = acc;
    }

    // ---- GEMM x-part (reads ws1, wsb, xt) ----
#pragma unroll 4
    for (int k = 0; k < KC; ++k) {
      const float4 w1 = *reinterpret_cast<const float4*>(&ws1[k][j0]);
      const float4 wb = *reinterpret_cast<const float4*>(&wsb[k][j0]);
      const float4 xv = *reinterpret_cast<const float4*>(&xt[k][tok0]);
      const float xs4[4] = {xv.x, xv.y, xv.z, xv.w};
#pragma unroll
      for (int i = 0; i < 4; ++i) {
        a1[i][0] = fmaf(xs4[i], w1.x, a1[i][0]);
        a1[i][1] = fmaf(xs4[i], w1.y, a1[i][1]);
        a1[i][2] = fmaf(xs4[i], w1.z, a1[i][2]);
        a1[i][3] = fmaf(xs4[i], w1.w, a1[i][3]);
        a2[i][0] = fmaf(xs4[i], wb.x, a2[i][0]);
        a2[i][1] = fmaf(xs4[i], wb.y, a2[i][1]);
        a2[i][2] = fmaf(xs4[i], wb.z, a2[i][2]);
        a2[i][3] = fmaf(xs4[i], wb.w, a2[i][3]);
      }
    }
    __syncthreads();   // (B) pf visible; ws1/wsb/xt reads all done

    // ---- hardware-async prefetch of chunk c+1 (cover = pf-GEMM below) ----
    if (c + 1 < NCH) {
      ISSUE_WEIGHTS(c + 1);   // ws1/wsb single-buf (safe: reads done), wsp flip
      LOAD_REGS(c + 1);
    }

    // ---- GEMM pf-part (reads wsp[c&1], pf) ----
    {
      const float (*wspc)[128] = wsp[c & 1];
#pragma unroll 4
      for (int oo = 0; oo < 8; ++oo) {
        const float4 wp = *reinterpret_cast<const float4*>(&wspc[oo][j0]);
        const float4 pv = *reinterpret_cast<const float4*>(&pf[oo][tok0]);
        const float ps4[4] = {pv.x, pv.y, pv.z, pv.w};
#pragma unroll
        for (int i = 0; i < 4; ++i) {
          a2[i][0] = fmaf(ps4[i], wp.x, a2[i][0]);
          a2[i][1] = fmaf(ps4[i], wp.y, a2[i][1]);
          a2[i][2] = fmaf(ps4[i], wp.z, a2[i][2]);
          a2[i][3] = fmaf(ps4[i], wp.w, a2[i][3]);
        }
      }
    }

    // ---- write next xt (xt free since barrier B; pf-GEMM doesn't read it) ----
    if (c + 1 < NCH) WRITE_XT();
  }

  // ---- epilogue: relu, project, cross-jq reduce, sigmoid ----
  {
    float b1v[4], w2v[4], bbv[4], wv2[4];
#pragma unroll
    for (int jj = 0; jj < 4; ++jj) {
      b1v[jj] = b1[j0 + jj];  w2v[jj] = W2[j0 + jj];
      bbv[jj] = bb1[j0 + jj]; wv2[jj] = Wb2[j0 + jj];
    }
    const float bias2 = b2[0], biasb2 = bb2[0];
#pragma unroll
    for (int i = 0; i < 4; ++i) {
      float p1 = 0.f, p2 = 0.f;
#pragma unroll
      for (int jj = 0; jj < 4; ++jj) {
        const float h1 = a1[i][jj] + b1v[jj];
        if (h1 > 0.f) p1 = fmaf(h1, w2v[jj], p1);
        const float h2 = a2[i][jj] + bbv[jj];
        if (h2 > 0.f) p2 = fmaf(h2, wv2[jj], p2);
      }
#pragma unroll
      for (int off = 1; off < 32; off <<= 1) {
        p1 += __shfl_xor(p1, off, 64);
        p2 += __shfl_xor(p2, off, 64);
      }
      if (jq == 0) {
        const int gi = b * L_ + l0 + tok0 + i;
        const float content = 1.f / (1.f + expf(-(p1 + bias2)));
        const float bscore  = 1.f / (1.f + expf(-(p2 + biasb2)));
        signal[gi] = content * (1.f - bscore) * mask[gi];
      }
    }
  }

  // ---- e epilogue: reduce over the 4 skk lanes of each token ----
  if (t < 128) {
    float es = esacc;
    es += __shfl_xor(es, 1, 64);
    es += __shfl_xor(es, 2, 64);
    if (skk == 0) {
      const int gi = b * L_ + l0 + stok;
      const float m = mask[gi];
      e[gi] = m * m * es;
    }
  }
#undef ISSUE_WEIGHTS
#undef LOAD_REGS
#undef WRITE_XT
}

// ---------------------------------------------------------------------------
// Fused quantile + enforce. One block (1024 thr) per batch row.
// ---------------------------------------------------------------------------
__device__ __forceinline__ int chain_sim(unsigned long long w, int from) {
  int last = -1;
  while (from < 64) {
    const unsigned long long m = w & (~0ull << from);
    if (m == 0ull) break;
    const int p = __ffsll(m) - 1;
    last = p;
    from = p + 4;
  }
  return last;
}

__global__ __launch_bounds__(1024) void k_select(
    const float* __restrict__ signal,
    int* __restrict__ starts, int* __restrict__ nlast, float* __restrict__ bounds)
{
  __shared__ unsigned int bins[4][256];
  __shared__ unsigned int sel_prefix;
  __shared__ int sel_rank;
  __shared__ float sh_thr;
  __shared__ unsigned int wmin[16];
  __shared__ int wcnt[16];
  __shared__ unsigned long long cw[128];
  __shared__ unsigned char nb[L_];
  __shared__ signed char tbl[128][4];
  __shared__ int st_in[128];
  __shared__ int tsum[256];
  __shared__ int offs[257];

  const int b = blockIdx.x, t = threadIdx.x;
  const int wv = t >> 6, lane = t & 63;
  const float* s = signal + b * L_;

  float val[8];
  unsigned int key[8];
#pragma unroll
  for (int i = 0; i < 8; ++i) {
    val[i] = s[(i << 10) + t];
    const unsigned int u = __float_as_uint(val[i]);
    key[i] = (u & 0x80000000u) ? ~u : (u | 0x80000000u);
  }

  // ---- radix select rank 5733 = floor(0.7*(L-1)) ----
  if (t == 0) { sel_prefix = 0u; sel_rank = 5733; }
  __syncthreads();
  for (int round = 0; round < 4; ++round) {
    reinterpret_cast<unsigned int*>(bins)[t] = 0u;
    __syncthreads();
    const unsigned int pre = sel_prefix;
    const int shift = 24 - 8 * round;
    if (round < 2) {
#pragma unroll
      for (int i = 0; i < 8; ++i) {
        const bool act = (round == 0) || ((key[i] >> (shift + 8)) == pre);
        const unsigned int bin = (key[i] >> shift) & 255u;
        unsigned long long peers = __ballot(act);
#pragma unroll
        for (int bit = 0; bit < 8; ++bit) {
          const bool myb = (bin >> bit) & 1;
          const unsigned long long bb = __ballot(act && myb);
          peers &= myb ? bb : ~bb;
        }
        if (act) {
          const int leader = __ffsll(peers) - 1;
          if (lane == leader)
            atomicAdd(&bins[wv >> 2][bin], (unsigned int)__popcll(peers));
        }
      }
    } else {
#pragma unroll
      for (int i = 0; i < 8; ++i) {
        if ((key[i] >> (shift + 8)) == pre)
          atomicAdd(&bins[wv >> 2][(key[i] >> shift) & 255u], 1u);
      }
    }
    __syncthreads();
    if (t < 256)
      bins[0][t] = bins[0][t] + bins[1][t] + bins[2][t] + bins[3][t];
    __syncthreads();
    if (t < 64) {
      const unsigned int c0 = bins[0][(t << 2) + 0], c1 = bins[0][(t << 2) + 1];
      const unsigned int c2 = bins[0][(t << 2) + 2], c3 = bins[0][(t << 2) + 3];
      const unsigned int lsum = c0 + c1 + c2 + c3;
      unsigned int run = lsum;
#pragma unroll
      for (int off = 1; off < 64; off <<= 1) {
        const unsigned int v = __shfl_up(run, off, 64);
        if (t >= off) run += v;
      }
      const int r = sel_rank;
      if (r >= (int)(run - lsum) && r < (int)run) {
        int rr = r - (int)(run - lsum);
        unsigned int cbin;
        if (rr < (int)c0) { cbin = 0; }
        else if (rr < (int)(c0 + c1)) { cbin = 1; rr -= (int)c0; }
        else if (rr < (int)(c0 + c1 + c2)) { cbin = 2; rr -= (int)(c0 + c1); }
        else { cbin = 3; rr -= (int)(c0 + c1 + c2); }
        sel_rank = rr;
        sel_prefix = (pre << 8) | ((unsigned int)(t << 2) | cbin);
      }
    }
    __syncthreads();
  }
  const unsigned int k0 = sel_prefix;

  // ---- successor: count <=k0 and min of keys > k0 (tie-safe) ----
  {
    int cle = 0;
    unsigned int mgt = 0xFFFFFFFFu;
#pragma unroll
    for (int i = 0; i < 8; ++i) {
      if (key[i] <= k0) ++cle;
      else mgt = min(mgt, key[i]);
    }
#pragma unroll
    for (int off = 1; off < 64; off <<= 1) {
      cle += __shfl_xor(cle, off, 64);
      mgt = min(mgt, (unsigned int)__shfl_xor((int)mgt, off, 64));
    }
    if (lane == 0) { wcnt[wv] = cle; wmin[wv] = mgt; }
    __syncthreads();
    if (t == 0) {
      int C = 0; unsigned int M = 0xFFFFFFFFu;
      for (int g = 0; g < 16; ++g) { C += wcnt[g]; M = min(M, wmin[g]); }
      const unsigned int k1 = (C >= 5735) ? k0 : M;
      const unsigned int u0 = (k0 & 0x80000000u) ? (k0 & 0x7fffffffu) : ~k0;
      const unsigned int u1 = (k1 & 0x80000000u) ? (k1 & 0x7fffffffu) : ~k1;
      const float v0 = __uint_as_float(u0);
      const float v1 = __uint_as_float(u1);
      const float g = 0.7f * 8191.0f - 5733.0f;
      sh_thr = v0 + g * (v1 - v0);
    }
    __syncthreads();
  }
  const float thr = sh_thr;

  // ---- candidate bitmap from register values ----
#pragma unroll
  for (int i = 0; i < 8; ++i) {
    const unsigned long long m = __ballot(val[i] < thr);
    if (lane == 0) cw[(i << 4) + wv] = m;
  }
  {
    const int base = t << 3;
#pragma unroll
    for (int i = 0; i < 8; ++i) nb[base + i] = 0;
  }
  __syncthreads();
  if (t == 0) cw[127] |= (1ull << 63);   // forced candidate at L-1
  __syncthreads();

  // ---- (1) per-64-block transition tables ----
  if (t < 512) {
    const int blk = t >> 2, cls = t & 3;
    tbl[blk][cls] = (signed char)chain_sim(cw[blk], cls);
  }
  __syncthreads();

  // ---- (2) serial 128-step state scan ----
  if (t == 0) {
    int st = 0;
    for (int blk = 0; blk < 128; ++blk) {
      const int bs = blk << 6;
      st_in[blk] = st;
      int pl;
      if (blk == 0) {
        pl = chain_sim(cw[0], 4);
      } else {
        int off = st + 4 - bs;
        if (off < 0) off = 0;
        pl = tbl[blk][off];
      }
      if (pl >= 0) st = bs + pl;
    }
  }
  __syncthreads();

  // ---- (3) parallel emission of acceptance + split bytes ----
  if (t < 128) {
    const int bs = t << 6;
    const unsigned long long w = cw[t];
    int st = st_in[t];
    int from = st + 4 - bs;
    if (from < 0) from = 0;
    while (from < 64) {
      const unsigned long long m = w & (~0ull << from);
      if (m == 0ull) break;
      const int p_rel = __ffsll(m) - 1;
      const int p = bs + p_rel;
      nb[p] = 1;
      const int ps = p - st;
      const int k = (ps + 15) >> 4;
      if (k > 1) {
        int sz = ps / k; if (sz < 1) sz = 1;
        for (int j = 1; j < k; ++j) nb[st + j * sz] = 1;
      }
      st = p;
      from = p_rel + 4;
    }
  }
  __syncthreads();

  // ---- prefix scan -> starts / nlast / bounds ----
  if (t < 256) {
    const int base = t << 5;
    int ls = 0;
    for (int i = 0; i < 32; ++i) ls += nb[base + i];
    tsum[t] = ls;
  }
  __syncthreads();
  if (t == 0) {
    int r = 0;
    for (int i = 0; i < 256; ++i) { offs[i] = r; r += tsum[i]; }
    offs[256] = r;
  }
  __syncthreads();
  if (t < 256) {
    const int base = t << 5;
    int run = offs[t];
    for (int i = 0; i < 32; ++i) {
      run += nb[base + i];
      if (nb[base + i]) starts[b * L_ + run] = base + i;
    }
  }
  if (t == 0) { starts[b * L_ + 0] = 0; nlast[b] = offs[256]; }
  __syncthreads();
  const int total = offs[256];
  for (int i = t; i < L_; i += 1024)
    bounds[b * L_ + i] = (i >= 1 && i <= total) ? 1.0f : 0.0f;
}

// ---------------------------------------------------------------------------
// Segment softmax-merge: 4 waves/block, one sid per wave. eb/mask loaded
// lane-parallel; max/den via shfl butterfly; per-token weight via __shfl.
// ---------------------------------------------------------------------------
__global__ __launch_bounds__(256) void k_merge(const float* __restrict__ x,
    const float* __restrict__ mask, const float* __restrict__ e,
    const int* __restrict__ starts, const int* __restrict__ nlast,
    float* __restrict__ merged)
{
  const int wv = threadIdx.x >> 6, lane = threadIdx.x & 63;
  const int idx = (blockIdx.x << 2) + wv;   // 0..32767
  const int b   = idx >> 13;
  const int sid = idx & (L_ - 1);
  const int n = nlast[b];
  const int c0 = lane << 3;
  float* o = merged + (size_t)(b * L_ + sid) * D_ + c0;
  if (sid > n) {
    const float4 z = make_float4(0.f, 0.f, 0.f, 0.f);
    reinterpret_cast<float4*>(o)[0] = z;
    reinterpret_cast<float4*>(o)[1] = z;
    return;
  }
  const int t0 = starts[b * L_ + sid];
  const int t1 = (sid < n) ? starts[b * L_ + sid + 1] : L_;
  const int len = t1 - t0;
  const float* eb = e + b * L_;
  const float* mk = mask + b * L_;

  // ---- max over segment (chunks of 64, lane-parallel) ----
  float mx = -INFINITY;
  for (int base = 0; base < len; base += 64) {
    const int p = base + lane;
    float m = (p < len) ? eb[t0 + p] : -INFINITY;
#pragma unroll
    for (int off = 32; off > 0; off >>= 1)
      m = fmaxf(m, __shfl_xor(m, off, 64));
    mx = fmaxf(mx, m);
  }
  // ---- denominator; cache first-chunk weight per lane ----
  float den = 0.f, w0 = 0.f;
  for (int base = 0; base < len; base += 64) {
    const int p = base + lane;
    float w = (p < len) ? expf(eb[t0 + p] - mx) : 0.f;
    if (base == 0) w0 = w;
    float sthis = w;
#pragma unroll
    for (int off = 32; off > 0; off >>= 1)
      sthis += __shfl_xor(sthis, off, 64);
    den += sthis;
  }
  // ---- weighted accumulation; 1-deep pipelined x-row loads ----
  float acc[8] = {0,0,0,0,0,0,0,0};
  for (int base = 0; base < len; base += 64) {
    const int p = base + lane;
    const float w = (base == 0) ? w0 : ((p < len) ? expf(eb[t0 + p] - mx) : 0.f);
    const float scl = (p < len) ? (w / den) * mk[t0 + p] : 0.f;
    const int cnt = (len - base < 64) ? (len - base) : 64;
    const float* xr0 = x + (size_t)(b * L_ + t0 + base) * D_ + c0;
    float4 u0 = reinterpret_cast<const float4*>(xr0)[0];
    float4 u1 = reinterpret_cast<const float4*>(xr0)[1];
    for (int q = 0; q < cnt; ++q) {
      float4 v0, v1;
      if (q + 1 < cnt) {
        const float* xr = xr0 + (size_t)(q + 1) * D_;
        v0 = reinterpret_cast<const float4*>(xr)[0];
        v1 = reinterpret_cast<const float4*>(xr)[1];
      }
      const float sc = __shfl(scl, q, 64);
      acc[0] = fmaf(sc, u0.x, acc[0]); acc[1] = fmaf(sc, u0.y, acc[1]);
      acc[2] = fmaf(sc, u0.z, acc[2]); acc[3] = fmaf(sc, u0.w, acc[3]);
      acc[4] = fmaf(sc, u1.x, acc[4]); acc[5] = fmaf(sc, u1.y, acc[5]);
      acc[6] = fmaf(sc, u1.z, acc[6]); acc[7] = fmaf(sc, u1.w, acc[7]);
      u0 = v0; u1 = v1;
    }
  }
  reinterpret_cast<float4*>(o)[0] = make_float4(acc[0], acc[1], acc[2], acc[3]);
  reinterpret_cast<float4*>(o)[1] = make_float4(acc[4], acc[5], acc[6], acc[7]);
}

// ---------------------------------------------------------------------------
extern "C" void kernel_launch(void* const* d_in, const int* in_sizes, int n_in,
                              void* d_out, int out_size, void* d_ws, size_t ws_size,
                              hipStream_t stream) {
  (void)in_sizes; (void)n_in; (void)out_size; (void)ws_size;
  const float* x    = (const float*)d_in[0];
  const float* mask = (const float*)d_in[1];
  const float* W1   = (const float*)d_in[2];
  const float* b1   = (const float*)d_in[3];
  const float* W2   = (const float*)d_in[4];
  const float* b2   = (const float*)d_in[5];
  const float* Wc   = (const float*)d_in[6];
  const float* bc   = (const float*)d_in[7];
  const float* Wb1  = (const float*)d_in[8];
  const float* bb1  = (const float*)d_in[9];
  const float* Wb2  = (const float*)d_in[10];
  const float* bb2  = (const float*)d_in[11];

  float* merged = (float*)d_out;
  float* bounds = (float*)d_out + (size_t)BL_ * D_;

  char* ws = (char*)d_ws;
  float* signal = (float*)(ws);
  float* e      = (float*)(ws + (size_t)BL_ * 4);
  int*   starts = (int*)  (ws + (size_t)BL_ * 8);
  int*   nlast  = (int*)  (ws + (size_t)BL_ * 12);

  k_signal<<<BL_ / TOK, 256, 0, stream>>>(x, mask, W1, b1, W2, b2, Wc, bc,
                                          Wb1, bb1, Wb2, bb2, signal, e);
  k_select<<<B_, 1024, 0, stream>>>(signal, starts, nlast, bounds);
  k_merge<<<BL_ / 4, 256, 0, stream>>>(x, mask, e, starts, nlast, merged);
}